// Round 14
// baseline (637.879 us; speedup 1.0000x reference)
//
#include <hip/hip_runtime.h>
#include <math.h>

typedef __attribute__((ext_vector_type(8))) __bf16 bf16x8;
typedef __attribute__((ext_vector_type(4))) float f32x4;
typedef __attribute__((ext_vector_type(2))) float f32x2;

#define DEV __device__ __forceinline__

typedef __attribute__((address_space(3))) unsigned int lds_u32;
typedef __attribute__((address_space(1))) unsigned int glb_u32;

DEV unsigned short f2bf(float f) {
    unsigned int u = __builtin_bit_cast(unsigned int, f);
    u += 0x7FFFu + ((u >> 16) & 1u);
    return (unsigned short)(u >> 16);
}
DEV float bf2f(unsigned short u) {
    unsigned int v = (unsigned int)u << 16;
    return __builtin_bit_cast(float, v);
}
DEV unsigned int pack2(float a, float b) {
    return (unsigned int)f2bf(a) | ((unsigned int)f2bf(b) << 16);
}
DEV float gelu_exact(float v) {
    return 0.5f * v * (1.0f + erff(v * 0.70710678118654752f));
}
// tanh-form gelu via sigmoid: x * sigmoid(1.595769x + 0.0713548x^3); |err| <= 3e-3
DEV float gelu_fast(float x) {
    float z = 1.5957691216f * x + 0.0713548163f * x * x * x;
    float e = __expf(-z);
    return x * __builtin_amdgcn_rcpf(1.0f + e);
}

// ---------------------------------------------------------------------------
// small prep kernels
// ---------------------------------------------------------------------------
__global__ void cast_bf16_kernel(const float* __restrict__ src,
                                 unsigned short* __restrict__ dst, int n) {
    int i = blockIdx.x * 256 + threadIdx.x;
    if (i < n) dst[i] = f2bf(src[i]);
}

__global__ void cast_fw1_kernel(const float* __restrict__ src,
                                unsigned short* __restrict__ dst) {
    int i = blockIdx.x * 256 + threadIdx.x;
    if (i < 2048 * 512) {
        int row = i >> 9, k = i & 511;
        dst[i] = f2bf(src[row * 514 + k]);
    }
}

__global__ void gb_kernel(const float* __restrict__ x,
                          const float* __restrict__ LW1, const float* __restrict__ Lb1,
                          const float* __restrict__ LW2, const float* __restrict__ Lb2,
                          float* __restrict__ gb) {
    __shared__ float t[8][512];
    const int b0 = blockIdx.x * 8, tid = threadIdx.x;
    for (int idx = tid; idx < 8 * 512; idx += 256) {
        int bb = idx >> 9, j = idx & 511;
        float s0 = x[((size_t)(b0 + bb) * 256 + 128) * 514 + 512];
        float s1 = x[((size_t)(b0 + bb) * 256 + 128) * 514 + 513];
        t[bb][j] = gelu_exact(LW1[j * 2] * s0 + LW1[j * 2 + 1] * s1 + Lb1[j]);
    }
    __syncthreads();
    const int i = tid;
    float a0[8], a1[8];
    float l0 = Lb2[i], l1 = Lb2[i + 256];
    #pragma unroll
    for (int bb = 0; bb < 8; ++bb) { a0[bb] = l0; a1[bb] = l1; }
    for (int j = 0; j < 512; ++j) {
        float w0 = LW2[(size_t)i * 512 + j];
        float w1 = LW2[(size_t)(i + 256) * 512 + j];
        #pragma unroll
        for (int bb = 0; bb < 8; ++bb) {
            a0[bb] += w0 * t[bb][j];
            a1[bb] += w1 * t[bb][j];
        }
    }
    #pragma unroll
    for (int bb = 0; bb < 8; ++bb) {
        gb[(size_t)(b0 + bb) * 512 + i] = a0[bb];
        gb[(size_t)(b0 + bb) * 512 + i + 256] = a1[bb];
    }
}

__global__ void sc_copy_kernel(const float* __restrict__ x, float* __restrict__ out,
                               float* __restrict__ scbuf) {
    size_t idx = (size_t)blockIdx.x * 256 + threadIdx.x;
    size_t off = idx * 514 + 512;
    f32x2 v = *(const f32x2*)(x + off);
    *(f32x2*)(out + off) = v;
    *(f32x2*)(scbuf + idx * 2) = v;
}

// ---------------------------------------------------------------------------
// mixer v8 (round-11 proven): two-phase x staging, 2-deep B prefetch.
// ---------------------------------------------------------------------------
#define MPAD 264

__global__ __launch_bounds__(256, 2) void mixer_kernel(
    const float* __restrict__ x, const float* __restrict__ bs,
    const float* __restrict__ Hb1, const float* __restrict__ Hb2,
    const unsigned short* __restrict__ Wsb,
    const unsigned short* __restrict__ HW1b,
    const unsigned short* __restrict__ HW2b,
    const float* __restrict__ gb,
    unsigned short* __restrict__ Xb) {
    __shared__ __attribute__((aligned(16))) char smem[33792 + 34816];
    unsigned short* XT = (unsigned short*)smem;
    unsigned short* S = (unsigned short*)(smem + 33792);
    unsigned short* ST = S;

    const int bid = blockIdx.x;
    const int b = bid >> 3;
    const int h = bid & 7;
    const int tid = threadIdx.x;
    const int lane = tid & 63;
    const int w = tid >> 6;
    const int l15 = lane & 15;
    const int l4 = lane >> 4;

    {
        const int c = lane;
        const float* xp = x + ((size_t)b * 256) * 514 + (size_t)h * 64 + c;
        float v[64];
        #pragma unroll
        for (int p = 0; p < 64; ++p)
            v[p] = xp[(size_t)(w * 64 + p) * 514];
        #pragma unroll
        for (int g = 0; g < 8; ++g) {
            uint4 pk;
            pk.x = pack2(v[g * 8 + 0], v[g * 8 + 1]);
            pk.y = pack2(v[g * 8 + 2], v[g * 8 + 3]);
            pk.z = pack2(v[g * 8 + 4], v[g * 8 + 5]);
            pk.w = pack2(v[g * 8 + 6], v[g * 8 + 7]);
            *(uint4*)&XT[c * MPAD + w * 64 + g * 8] = pk;
        }
    }
    __syncthreads();

    f32x4 acc[4][4];

    #pragma unroll
    for (int mt = 0; mt < 4; ++mt)
        #pragma unroll
        for (int nt = 0; nt < 4; ++nt) acc[mt][nt] = 0.f;
    {
        const unsigned short* Wp = Wsb;
        bf16x8 bn1[4], bn2[4];
        #pragma unroll
        for (int nt = 0; nt < 4; ++nt) {
            bn1[nt] = *(const bf16x8*)(Wp + (size_t)(w * 64 + nt * 16 + l15) * 256 + 0 * 32 + l4 * 8);
            bn2[nt] = *(const bf16x8*)(Wp + (size_t)(w * 64 + nt * 16 + l15) * 256 + 1 * 32 + l4 * 8);
        }
        for (int kc = 0; kc < 8; ++kc) {
            bf16x8 bcur[4];
            #pragma unroll
            for (int nt = 0; nt < 4; ++nt) { bcur[nt] = bn1[nt]; bn1[nt] = bn2[nt]; }
            if (kc < 6) {
                #pragma unroll
                for (int nt = 0; nt < 4; ++nt)
                    bn2[nt] = *(const bf16x8*)(Wp + (size_t)(w * 64 + nt * 16 + l15) * 256 + (kc + 2) * 32 + l4 * 8);
            }
            #pragma unroll
            for (int mt = 0; mt < 4; ++mt) {
                bf16x8 afr = *(const bf16x8*)&XT[(mt * 16 + l15) * MPAD + kc * 32 + l4 * 8];
                #pragma unroll
                for (int nt = 0; nt < 4; ++nt)
                    acc[mt][nt] = __builtin_amdgcn_mfma_f32_16x16x32_bf16(afr, bcur[nt], acc[mt][nt], 0, 0, 0);
            }
        }
    }
    #pragma unroll
    for (int nt = 0; nt < 4; ++nt) {
        int o = w * 64 + nt * 16 + l15;
        float bsv = bs[o];
        float g = gb[(size_t)b * 512 + o];
        float be = gb[(size_t)b * 512 + 256 + o];
        #pragma unroll
        for (int mt = 0; mt < 4; ++mt)
            #pragma unroll
            for (int r = 0; r < 4; ++r) {
                int c = mt * 16 + l4 * 4 + r;
                S[c * MPAD + o] = f2bf((acc[mt][nt][r] + bsv) * g + be);
            }
    }
    __syncthreads();

    const unsigned short* W2p = HW1b + (size_t)h * 65536;
    #pragma unroll
    for (int mt = 0; mt < 4; ++mt)
        #pragma unroll
        for (int nt = 0; nt < 4; ++nt) acc[mt][nt] = 0.f;
    {
        bf16x8 bn1[4], bn2[4];
        #pragma unroll
        for (int nt = 0; nt < 4; ++nt) {
            bn1[nt] = *(const bf16x8*)(W2p + (size_t)(w * 64 + nt * 16 + l15) * 256 + 0 * 32 + l4 * 8);
            bn2[nt] = *(const bf16x8*)(W2p + (size_t)(w * 64 + nt * 16 + l15) * 256 + 1 * 32 + l4 * 8);
        }
        for (int kc = 0; kc < 8; ++kc) {
            bf16x8 bcur[4];
            #pragma unroll
            for (int nt = 0; nt < 4; ++nt) { bcur[nt] = bn1[nt]; bn1[nt] = bn2[nt]; }
            if (kc < 6) {
                #pragma unroll
                for (int nt = 0; nt < 4; ++nt)
                    bn2[nt] = *(const bf16x8*)(W2p + (size_t)(w * 64 + nt * 16 + l15) * 256 + (kc + 2) * 32 + l4 * 8);
            }
            #pragma unroll
            for (int mt = 0; mt < 4; ++mt) {
                bf16x8 afr = *(const bf16x8*)&S[(mt * 16 + l15) * MPAD + kc * 32 + l4 * 8];
                #pragma unroll
                for (int nt = 0; nt < 4; ++nt)
                    acc[mt][nt] = __builtin_amdgcn_mfma_f32_16x16x32_bf16(afr, bcur[nt], acc[mt][nt], 0, 0, 0);
            }
        }
    }
    __syncthreads();
    #pragma unroll
    for (int nt = 0; nt < 4; ++nt) {
        int kk = w * 64 + nt * 16 + l15;
        float hb = Hb1[(size_t)h * 256 + kk];
        #pragma unroll
        for (int mt = 0; mt < 4; ++mt)
            #pragma unroll
            for (int r = 0; r < 4; ++r) {
                int c = mt * 16 + l4 * 4 + r;
                S[c * MPAD + kk] = f2bf(gelu_fast(acc[mt][nt][r] + hb));
            }
    }
    __syncthreads();

    const unsigned short* W3p = HW2b + (size_t)h * 65536;
    #pragma unroll
    for (int mt = 0; mt < 4; ++mt)
        #pragma unroll
        for (int nt = 0; nt < 4; ++nt) acc[mt][nt] = 0.f;
    {
        bf16x8 bn1[4], bn2[4];
        #pragma unroll
        for (int nt = 0; nt < 4; ++nt) {
            bn1[nt] = *(const bf16x8*)(W3p + (size_t)(w * 64 + nt * 16 + l15) * 256 + 0 * 32 + l4 * 8);
            bn2[nt] = *(const bf16x8*)(W3p + (size_t)(w * 64 + nt * 16 + l15) * 256 + 1 * 32 + l4 * 8);
        }
        for (int kc = 0; kc < 8; ++kc) {
            bf16x8 bcur[4];
            #pragma unroll
            for (int nt = 0; nt < 4; ++nt) { bcur[nt] = bn1[nt]; bn1[nt] = bn2[nt]; }
            if (kc < 6) {
                #pragma unroll
                for (int nt = 0; nt < 4; ++nt)
                    bn2[nt] = *(const bf16x8*)(W3p + (size_t)(w * 64 + nt * 16 + l15) * 256 + (kc + 2) * 32 + l4 * 8);
            }
            #pragma unroll
            for (int mt = 0; mt < 4; ++mt) {
                bf16x8 afr = *(const bf16x8*)&S[(mt * 16 + l15) * MPAD + kc * 32 + l4 * 8];
                #pragma unroll
                for (int nt = 0; nt < 4; ++nt)
                    acc[mt][nt] = __builtin_amdgcn_mfma_f32_16x16x32_bf16(afr, bcur[nt], acc[mt][nt], 0, 0, 0);
            }
        }
    }
    __syncthreads();

    #pragma unroll
    for (int nt = 0; nt < 4; ++nt) {
        int p = w * 64 + nt * 16 + l15;
        float hb = Hb2[(size_t)h * 256 + p];
        #pragma unroll
        for (int mt = 0; mt < 4; ++mt) {
            int c0 = mt * 16 + l4 * 4;
            ushort4 uv;
            uv.x = f2bf(acc[mt][nt][0] + hb + bf2f(XT[(c0 + 0) * MPAD + p]));
            uv.y = f2bf(acc[mt][nt][1] + hb + bf2f(XT[(c0 + 1) * MPAD + p]));
            uv.z = f2bf(acc[mt][nt][2] + hb + bf2f(XT[(c0 + 2) * MPAD + p]));
            uv.w = f2bf(acc[mt][nt][3] + hb + bf2f(XT[(c0 + 3) * MPAD + p]));
            *(ushort4*)(ST + p * 68 + c0) = uv;
        }
    }
    __syncthreads();

    #pragma unroll
    for (int s = 0; s < 16; ++s) {
        int row = s * 16 + w * 4 + l4;
        ushort4 u = *(const ushort4*)(ST + row * 68 + l15 * 4);
        *(ushort4*)(Xb + ((size_t)(b * 256 + row)) * 512 + h * 64 + l15 * 4) = u;
    }
}

// ---------------------------------------------------------------------------
// GEMM v6: m201-style 8-phase 256x256, BK=64, 512 thr / 8 waves (2M x 4N,
// wave tile 128x64). K-tile = 4 phases; ALL 24 ds_reads front-loaded into
// phases 0-1 (fragments held in regs) so buffer halves free from phase 2.
// 1 half-tile staged per phase; counted vmcnt(6) ONCE per tile (never 0
// mid-loop). Raw s_barrier + compiler memory fences; setprio around MFMA.
// Ledger (verified by induction): at tile T ph0 wait, vmcnt(6) confirms
// exactly T's 4 halves; 3 halves stay in flight.
// LDS 128KB: A[2][32K] @0, B[2][32K] @64K.
// ---------------------------------------------------------------------------
DEV void stage_half8(const unsigned short* g, size_t gstride, int row0, int k0,
                     char* half_base, int w, int lane) {
    const int slot = lane & 7;
    const int r8 = lane >> 3;
    const int swz = (slot ^ r8) * 16;
    #pragma unroll
    for (int i = 0; i < 2; ++i) {
        int chunk = w * 2 + i;  // 0..15
        int row = chunk * 8 + r8;
        const char* src = (const char*)(g + (size_t)(row0 + row) * gstride + k0) + swz;
        __builtin_amdgcn_global_load_lds((const glb_u32*)src,
                                         (lds_u32*)(half_base + chunk * 1024), 16, 0, 0);
    }
}

#define FENCE() asm volatile("" ::: "memory")

DEV void gemm_loop8(const unsigned short* A, size_t sA,
                    const unsigned short* B, size_t sB,
                    int m0, int n0, int NT,
                    char* smem, int w, int lane, f32x4 (&acc)[8][4]) {
    const int wm = w >> 2, wn = w & 3;
    const int l15 = lane & 15, l4 = lane >> 4;
    const int koff0 = (l4 * 16) ^ ((l15 & 7) << 4);
    const int koff1 = (64 + l4 * 16) ^ ((l15 & 7) << 4);

    // prologue: T0 all 4 halves + T1 A halves (12 loads/thread in flight)
    stage_half8(A, sA, m0, 0, smem, w, lane);                      // T0 Ah0
    stage_half8(A, sA, m0 + 128, 0, smem + 16384, w, lane);        // T0 Ah1
    stage_half8(B, sB, n0, 0, smem + 65536, w, lane);              // T0 Bh0
    stage_half8(B, sB, n0 + 128, 0, smem + 65536 + 16384, w, lane);// T0 Bh1
    stage_half8(A, sA, m0, 64, smem + 32768, w, lane);             // T1 Ah0
    stage_half8(A, sA, m0 + 128, 64, smem + 32768 + 16384, w, lane);// T1 Ah1

    for (int T = 0; T < NT; ++T) {
        const int cb = T & 1;
        const char* Ab = smem + cb * 32768;
        const char* Bb = smem + 65536 + cb * 32768;
        const int nbuf = cb ^ 1;

        // ---- phase 0: stage (T+1) Bh0; wait; read B(all)+A(mf0-3); MFMA mf0,1 ----
        if (T + 1 < NT)
            stage_half8(B, sB, n0, (T + 1) * 64, smem + 65536 + nbuf * 32768, w, lane);
        if (T == NT - 1) asm volatile("s_waitcnt vmcnt(0)" ::: "memory");
        else             asm volatile("s_waitcnt vmcnt(6)" ::: "memory");
        __builtin_amdgcn_s_barrier();
        FENCE();

        bf16x8 Bf[2][4], Alo[2][4], Ahi[2][4];
        #pragma unroll
        for (int kk = 0; kk < 2; ++kk) {
            const int ko = kk ? koff1 : koff0;
            #pragma unroll
            for (int nf = 0; nf < 4; ++nf) {
                int row = wn * 64 + nf * 16 + l15;
                Bf[kk][nf] = *(const bf16x8*)(Bb + row * 128 + ko);
            }
            #pragma unroll
            for (int mf = 0; mf < 4; ++mf) {
                int row = wm * 128 + mf * 16 + l15;
                Alo[kk][mf] = *(const bf16x8*)(Ab + row * 128 + ko);
            }
        }
        __builtin_amdgcn_s_setprio(1);
        #pragma unroll
        for (int kk = 0; kk < 2; ++kk)
            #pragma unroll
            for (int mf = 0; mf < 2; ++mf)
                #pragma unroll
                for (int nf = 0; nf < 4; ++nf)
                    acc[mf][nf] = __builtin_amdgcn_mfma_f32_16x16x32_bf16(
                        Alo[kk][mf], Bf[kk][nf], acc[mf][nf], 0, 0, 0);
        __builtin_amdgcn_s_setprio(0);
        __builtin_amdgcn_s_barrier();
        FENCE();

        // ---- phase 1: stage (T+1) Bh1; read A(mf4-7); MFMA mf2,3 ----
        if (T + 1 < NT)
            stage_half8(B, sB, n0 + 128, (T + 1) * 64, smem + 65536 + nbuf * 32768 + 16384, w, lane);
        #pragma unroll
        for (int kk = 0; kk < 2; ++kk) {
            const int ko = kk ? koff1 : koff0;
            #pragma unroll
            for (int mf = 0; mf < 4; ++mf) {
                int row = wm * 128 + (mf + 4) * 16 + l15;
                Ahi[kk][mf] = *(const bf16x8*)(Ab + row * 128 + ko);
            }
        }
        __builtin_amdgcn_s_setprio(1);
        #pragma unroll
        for (int kk = 0; kk < 2; ++kk)
            #pragma unroll
            for (int mf = 2; mf < 4; ++mf)
                #pragma unroll
                for (int nf = 0; nf < 4; ++nf)
                    acc[mf][nf] = __builtin_amdgcn_mfma_f32_16x16x32_bf16(
                        Alo[kk][mf], Bf[kk][nf], acc[mf][nf], 0, 0, 0);
        __builtin_amdgcn_s_setprio(0);
        __builtin_amdgcn_s_barrier();
        FENCE();

        // ---- phase 2: stage (T+2) Ah0 (buf cb now free); MFMA mf4,5 ----
        if (T + 2 < NT)
            stage_half8(A, sA, m0, (T + 2) * 64, smem + cb * 32768, w, lane);
        __builtin_amdgcn_s_setprio(1);
        #pragma unroll
        for (int kk = 0; kk < 2; ++kk)
            #pragma unroll
            for (int mf = 0; mf < 2; ++mf)
                #pragma unroll
                for (int nf = 0; nf < 4; ++nf)
                    acc[mf + 4][nf] = __builtin_amdgcn_mfma_f32_16x16x32_bf16(
                        Ahi[kk][mf], Bf[kk][nf], acc[mf + 4][nf], 0, 0, 0);
        __builtin_amdgcn_s_setprio(0);
        __builtin_amdgcn_s_barrier();
        FENCE();

        // ---- phase 3: stage (T+2) Ah1; MFMA mf6,7 ----
        if (T + 2 < NT)
            stage_half8(A, sA, m0 + 128, (T + 2) * 64, smem + cb * 32768 + 16384, w, lane);
        __builtin_amdgcn_s_setprio(1);
        #pragma unroll
        for (int kk = 0; kk < 2; ++kk)
            #pragma unroll
            for (int mf = 2; mf < 4; ++mf)
                #pragma unroll
                for (int nf = 0; nf < 4; ++nf)
                    acc[mf + 4][nf] = __builtin_amdgcn_mfma_f32_16x16x32_bf16(
                        Ahi[kk][mf], Bf[kk][nf], acc[mf + 4][nf], 0, 0, 0);
        __builtin_amdgcn_s_setprio(0);
        __builtin_amdgcn_s_barrier();
        FENCE();
    }
}

// GEMM1: G = gelu(Xb @ FW1b^T + Fb1 + sc0*w512 + sc1*w513), LDS-bounce G store
__global__ __launch_bounds__(512, 1) void gemm1_kernel(
    const unsigned short* __restrict__ A,
    const unsigned short* __restrict__ B,
    const float* __restrict__ Fb1,
    const float* __restrict__ FW1,
    const float* __restrict__ scbuf,
    long pass_m0,
    unsigned short* __restrict__ G) {
    __shared__ __attribute__((aligned(16))) char smem[131072];

    const int nwg = gridDim.x;
    const int cpx = nwg >> 3;
    const int bid = (blockIdx.x & 7) * cpx + (blockIdx.x >> 3);
    const int m0 = (bid >> 3) * 256;
    const int n0 = (bid & 7) * 256;
    const int tid = threadIdx.x;
    const int lane = tid & 63;
    const int w = tid >> 6;
    const int l15 = lane & 15;
    const int l4 = lane >> 4;
    const int wm = w >> 2, wn = w & 3;

    f32x4 acc[8][4];
    #pragma unroll
    for (int mf = 0; mf < 8; ++mf)
        #pragma unroll
        for (int nf = 0; nf < 4; ++nf) acc[mf][nf] = 0.f;

    gemm_loop8(A, 512, B, 512, m0, n0, 8, smem, w, lane, acc);
    __builtin_amdgcn_s_barrier();
    FENCE();

    // epilogue (round-8 verified): LT pitch 264 ushorts (528B), two halves
    float fb[4], wa[4], wb[4];
    #pragma unroll
    for (int nf = 0; nf < 4; ++nf) {
        int n = n0 + wn * 64 + nf * 16 + l15;
        fb[nf] = Fb1[n];
        wa[nf] = FW1[(size_t)n * 514 + 512];
        wb[nf] = FW1[(size_t)n * 514 + 513];
    }
    unsigned short* LT = (unsigned short*)smem;
    #pragma unroll
    for (int ph = 0; ph < 2; ++ph) {
        if (wm == ph) {
            #pragma unroll
            for (int mfg = 0; mfg < 8; ++mfg) {
                f32x2 sc[4];
                #pragma unroll
                for (int r = 0; r < 4; ++r) {
                    long rowg = pass_m0 + m0 + ph * 128 + mfg * 16 + l4 * 4 + r;
                    sc[r] = *(const f32x2*)(scbuf + rowg * 2);
                }
                #pragma unroll
                for (int nf = 0; nf < 4; ++nf)
                    #pragma unroll
                    for (int r = 0; r < 4; ++r) {
                        float v = acc[mfg][nf][r] + fb[nf] + sc[r].x * wa[nf] + sc[r].y * wb[nf];
                        int rl = mfg * 16 + l4 * 4 + r;
                        LT[rl * 264 + wn * 64 + nf * 16 + l15] = f2bf(gelu_fast(v));
                    }
            }
        }
        __syncthreads();
        {
            const int row16 = tid >> 5, col16 = tid & 31;
            #pragma unroll
            for (int sp = 0; sp < 8; ++sp) {
                int row = sp * 16 + row16;
                uint4 d = *(const uint4*)((const char*)smem + row * 528 + col16 * 16);
                *(uint4*)(G + ((size_t)(m0 + ph * 128 + row)) * 2048 + n0 + col16 * 8) = d;
            }
        }
        __syncthreads();
    }
}

// GEMM2: io[., 0..511] = G @ FW2b^T + Fb2 + bf2f(Xb)
__global__ __launch_bounds__(512, 1) void gemm2_kernel(
    const unsigned short* __restrict__ A,
    const unsigned short* __restrict__ B,
    const float* __restrict__ Fb2,
    const unsigned short* __restrict__ Xb,
    long pass_m0,
    float* __restrict__ io) {
    __shared__ __attribute__((aligned(16))) char smem[131072];

    const int nwg = gridDim.x;
    const int cpx = nwg >> 3;
    const int bid = (blockIdx.x & 7) * cpx + (blockIdx.x >> 3);
    const int m0 = (bid >> 1) * 256;
    const int n0 = (bid & 1) * 256;
    const int tid = threadIdx.x;
    const int lane = tid & 63;
    const int w = tid >> 6;
    const int l15 = lane & 15;
    const int l4 = lane >> 4;
    const int wm = w >> 2, wn = w & 3;

    f32x4 acc[8][4];
    #pragma unroll
    for (int mf = 0; mf < 8; ++mf)
        #pragma unroll
        for (int nf = 0; nf < 4; ++nf) acc[mf][nf] = 0.f;

    gemm_loop8(A, 2048, B, 2048, m0, n0, 32, smem, w, lane, acc);

    #pragma unroll
    for (int nf = 0; nf < 4; ++nf) {
        int n = n0 + wn * 64 + nf * 16 + l15;
        float fbv = Fb2[n];
        #pragma unroll
        for (int mfg = 0; mfg < 8; ++mfg)
            #pragma unroll
            for (int r = 0; r < 4; ++r) {
                long rowg = pass_m0 + m0 + wm * 128 + mfg * 16 + l4 * 4 + r;
                float resv = bf2f(Xb[(size_t)rowg * 512 + n]);
                io[rowg * 514 + n] = acc[mfg][nf][r] + fbv + resv;
            }
    }
}

// ---------------------------------------------------------------------------
extern "C" void kernel_launch(void* const* d_in, const int* in_sizes, int n_in,
                              void* d_out, int out_size, void* d_ws, size_t ws_size,
                              hipStream_t stream) {
    const float* x = (const float*)d_in[0];
    const float* Ws = (const float*)d_in[1];
    const float* bs = (const float*)d_in[2];
    const float* LW1 = (const float*)d_in[3];
    const float* Lb1 = (const float*)d_in[4];
    const float* LW2 = (const float*)d_in[5];
    const float* Lb2 = (const float*)d_in[6];
    const float* HW1 = (const float*)d_in[7];
    const float* Hb1 = (const float*)d_in[8];
    const float* HW2 = (const float*)d_in[9];
    const float* Hb2 = (const float*)d_in[10];
    const float* FW1 = (const float*)d_in[11];
    const float* Fb1 = (const float*)d_in[12];
    const float* FW2 = (const float*)d_in[13];
    const float* Fb2 = (const float*)d_in[14];
    float* out = (float*)d_out;

    char* ws = (char*)d_ws;
    unsigned short* Wsb = (unsigned short*)(ws);                 // 131072 B
    unsigned short* HW1b = (unsigned short*)(ws + 131072);       // 1048576 B
    unsigned short* HW2b = (unsigned short*)(ws + 1179648);      // 1048576 B
    unsigned short* FW1b = (unsigned short*)(ws + 2228224);      // 2097152 B
    unsigned short* FW2b = (unsigned short*)(ws + 4325376);      // 2097152 B
    float* gb = (float*)(ws + 6422528);                          // 524288 B
    float* scbuf = (float*)(ws + 6946816);                       // 524288 B
    unsigned short* Xb = (unsigned short*)(ws + 7471104);        // 67108864 B
    unsigned short* Gbuf = (unsigned short*)(ws + 7471104 + 67108864);

    const size_t fixed = 7471104 + 67108864;
    int npass = 32;
    for (int np = 2; np <= 32; np *= 2) {
        if (fixed + (size_t)268435456 / np <= ws_size) { npass = np; break; }
    }
    const long Mtot = 65536;
    const long Mp = Mtot / npass;

    cast_bf16_kernel<<<256, 256, 0, stream>>>(Ws, Wsb, 65536);
    cast_bf16_kernel<<<2048, 256, 0, stream>>>(HW1, HW1b, 524288);
    cast_bf16_kernel<<<2048, 256, 0, stream>>>(HW2, HW2b, 524288);
    cast_bf16_kernel<<<4096, 256, 0, stream>>>(FW2, FW2b, 1048576);
    cast_fw1_kernel<<<4096, 256, 0, stream>>>(FW1, FW1b);
    gb_kernel<<<32, 256, 0, stream>>>(x, LW1, Lb1, LW2, Lb2, gb);
    sc_copy_kernel<<<256, 256, 0, stream>>>(x, out, scbuf);

    mixer_kernel<<<2048, 256, 0, stream>>>(x, bs, Hb1, Hb2, Wsb, HW1b, HW2b, gb, Xb);

    for (int p = 0; p < npass; ++p) {
        long m0 = (long)p * Mp;
        gemm1_kernel<<<(int)(Mp / 256) * 8, 512, 0, stream>>>(
            Xb + m0 * 512, FW1b, Fb1, FW1, scbuf, m0, Gbuf);
        gemm2_kernel<<<(int)(Mp / 256) * 2, 512, 0, stream>>>(
            Gbuf, FW2b, Fb2, Xb, m0, out);
    }
}

// Round 15
// 597.854 us; speedup vs baseline: 1.0669x; 1.0669x over previous
//
#include <hip/hip_runtime.h>
#include <math.h>

typedef __attribute__((ext_vector_type(8))) __bf16 bf16x8;
typedef __attribute__((ext_vector_type(4))) float f32x4;
typedef __attribute__((ext_vector_type(2))) float f32x2;

#define DEV __device__ __forceinline__

typedef __attribute__((address_space(3))) unsigned int lds_u32;
typedef __attribute__((address_space(1))) unsigned int glb_u32;

DEV unsigned short f2bf(float f) {
    unsigned int u = __builtin_bit_cast(unsigned int, f);
    u += 0x7FFFu + ((u >> 16) & 1u);
    return (unsigned short)(u >> 16);
}
DEV float bf2f(unsigned short u) {
    unsigned int v = (unsigned int)u << 16;
    return __builtin_bit_cast(float, v);
}
DEV unsigned int pack2(float a, float b) {
    return (unsigned int)f2bf(a) | ((unsigned int)f2bf(b) << 16);
}
DEV float gelu_exact(float v) {
    return 0.5f * v * (1.0f + erff(v * 0.70710678118654752f));
}
// tanh-form gelu via sigmoid: x * sigmoid(1.595769x + 0.0713548x^3); |err| <= 3e-3
DEV float gelu_fast(float x) {
    float z = 1.5957691216f * x + 0.0713548163f * x * x * x;
    float e = __expf(-z);
    return x * __builtin_amdgcn_rcpf(1.0f + e);
}

// ---------------------------------------------------------------------------
// small prep kernels
// ---------------------------------------------------------------------------
__global__ void cast_bf16_kernel(const float* __restrict__ src,
                                 unsigned short* __restrict__ dst, int n) {
    int i = blockIdx.x * 256 + threadIdx.x;
    if (i < n) dst[i] = f2bf(src[i]);
}

__global__ void cast_fw1_kernel(const float* __restrict__ src,
                                unsigned short* __restrict__ dst) {
    int i = blockIdx.x * 256 + threadIdx.x;
    if (i < 2048 * 512) {
        int row = i >> 9, k = i & 511;
        dst[i] = f2bf(src[row * 514 + k]);
    }
}

__global__ void gb_kernel(const float* __restrict__ x,
                          const float* __restrict__ LW1, const float* __restrict__ Lb1,
                          const float* __restrict__ LW2, const float* __restrict__ Lb2,
                          float* __restrict__ gb) {
    __shared__ float t[8][512];
    const int b0 = blockIdx.x * 8, tid = threadIdx.x;
    for (int idx = tid; idx < 8 * 512; idx += 256) {
        int bb = idx >> 9, j = idx & 511;
        float s0 = x[((size_t)(b0 + bb) * 256 + 128) * 514 + 512];
        float s1 = x[((size_t)(b0 + bb) * 256 + 128) * 514 + 513];
        t[bb][j] = gelu_exact(LW1[j * 2] * s0 + LW1[j * 2 + 1] * s1 + Lb1[j]);
    }
    __syncthreads();
    const int i = tid;
    float a0[8], a1[8];
    float l0 = Lb2[i], l1 = Lb2[i + 256];
    #pragma unroll
    for (int bb = 0; bb < 8; ++bb) { a0[bb] = l0; a1[bb] = l1; }
    for (int j = 0; j < 512; ++j) {
        float w0 = LW2[(size_t)i * 512 + j];
        float w1 = LW2[(size_t)(i + 256) * 512 + j];
        #pragma unroll
        for (int bb = 0; bb < 8; ++bb) {
            a0[bb] += w0 * t[bb][j];
            a1[bb] += w1 * t[bb][j];
        }
    }
    #pragma unroll
    for (int bb = 0; bb < 8; ++bb) {
        gb[(size_t)(b0 + bb) * 512 + i] = a0[bb];
        gb[(size_t)(b0 + bb) * 512 + i + 256] = a1[bb];
    }
}

__global__ void sc_copy_kernel(const float* __restrict__ x, float* __restrict__ out,
                               float* __restrict__ scbuf) {
    size_t idx = (size_t)blockIdx.x * 256 + threadIdx.x;
    size_t off = idx * 514 + 512;
    f32x2 v = *(const f32x2*)(x + off);
    *(f32x2*)(out + off) = v;
    *(f32x2*)(scbuf + idx * 2) = v;
}

// ---------------------------------------------------------------------------
// mixer v11: v8 chain, staging replaced by coalesced row reads + LDS
// transpose writes (no extra HBM traffic, no separate transpose kernel).
// Per pass s: 16 threads cover one even/odd row pair's 64 channels.
//   even row: f32x4 (16B-aligned: 514p+64h+4cq = 0 mod 4 for even p)
//   odd row:  2x f32x2 (offset = 2 mod 4 -> only 8B-aligned)
// Writes: 4 u32 pack2(even,odd) at XT32[c*132 + p/2].
// ---------------------------------------------------------------------------
#define MPAD 264

__global__ __launch_bounds__(256, 2) void mixer_kernel(
    const float* __restrict__ x, const float* __restrict__ bs,
    const float* __restrict__ Hb1, const float* __restrict__ Hb2,
    const unsigned short* __restrict__ Wsb,
    const unsigned short* __restrict__ HW1b,
    const unsigned short* __restrict__ HW2b,
    const float* __restrict__ gb,
    unsigned short* __restrict__ Xb) {
    __shared__ __attribute__((aligned(16))) char smem[33792 + 34816];
    unsigned short* XT = (unsigned short*)smem;
    unsigned short* S = (unsigned short*)(smem + 33792);
    unsigned short* ST = S;

    const int bid = blockIdx.x;
    const int b = bid >> 3;
    const int h = bid & 7;
    const int tid = threadIdx.x;
    const int lane = tid & 63;
    const int w = tid >> 6;
    const int l15 = lane & 15;
    const int l4 = lane >> 4;

    // ---- stage x^T: coalesced reads, transposed packed LDS writes ----
    {
        const int pq = tid >> 4;   // 0..15 (p-pair within 32-row stripe)
        const int cq = tid & 15;   // 0..15 (channel quad)
        unsigned int* XT32 = (unsigned int*)XT;
        #pragma unroll
        for (int s = 0; s < 8; ++s) {
            int p = s * 32 + pq * 2;
            const float* r0 = x + ((size_t)(b * 256 + p)) * 514 + h * 64 + cq * 4;
            const float* r1 = r0 + 514;
            f32x4 av = *(const f32x4*)r0;
            f32x2 bv0 = *(const f32x2*)r1;
            f32x2 bv1 = *(const f32x2*)(r1 + 2);
            int pco = s * 16 + pq;  // p/2
            XT32[(cq * 4 + 0) * 132 + pco] = pack2(av.x, bv0.x);
            XT32[(cq * 4 + 1) * 132 + pco] = pack2(av.y, bv0.y);
            XT32[(cq * 4 + 2) * 132 + pco] = pack2(av.z, bv1.x);
            XT32[(cq * 4 + 3) * 132 + pco] = pack2(av.w, bv1.y);
        }
    }
    __syncthreads();

    f32x4 acc[4][4];

    // ---- stage 1: S[c][o] = (XT @ Ws^T + bs)*gamma + beta ----
    #pragma unroll
    for (int mt = 0; mt < 4; ++mt)
        #pragma unroll
        for (int nt = 0; nt < 4; ++nt) acc[mt][nt] = 0.f;
    {
        const unsigned short* Wp = Wsb;
        bf16x8 bn1[4], bn2[4];
        #pragma unroll
        for (int nt = 0; nt < 4; ++nt) {
            bn1[nt] = *(const bf16x8*)(Wp + (size_t)(w * 64 + nt * 16 + l15) * 256 + 0 * 32 + l4 * 8);
            bn2[nt] = *(const bf16x8*)(Wp + (size_t)(w * 64 + nt * 16 + l15) * 256 + 1 * 32 + l4 * 8);
        }
        for (int kc = 0; kc < 8; ++kc) {
            bf16x8 bcur[4];
            #pragma unroll
            for (int nt = 0; nt < 4; ++nt) { bcur[nt] = bn1[nt]; bn1[nt] = bn2[nt]; }
            if (kc < 6) {
                #pragma unroll
                for (int nt = 0; nt < 4; ++nt)
                    bn2[nt] = *(const bf16x8*)(Wp + (size_t)(w * 64 + nt * 16 + l15) * 256 + (kc + 2) * 32 + l4 * 8);
            }
            #pragma unroll
            for (int mt = 0; mt < 4; ++mt) {
                bf16x8 afr = *(const bf16x8*)&XT[(mt * 16 + l15) * MPAD + kc * 32 + l4 * 8];
                #pragma unroll
                for (int nt = 0; nt < 4; ++nt)
                    acc[mt][nt] = __builtin_amdgcn_mfma_f32_16x16x32_bf16(afr, bcur[nt], acc[mt][nt], 0, 0, 0);
            }
        }
    }
    #pragma unroll
    for (int nt = 0; nt < 4; ++nt) {
        int o = w * 64 + nt * 16 + l15;
        float bsv = bs[o];
        float g = gb[(size_t)b * 512 + o];
        float be = gb[(size_t)b * 512 + 256 + o];
        #pragma unroll
        for (int mt = 0; mt < 4; ++mt)
            #pragma unroll
            for (int r = 0; r < 4; ++r) {
                int c = mt * 16 + l4 * 4 + r;
                S[c * MPAD + o] = f2bf((acc[mt][nt][r] + bsv) * g + be);
            }
    }
    __syncthreads();

    // ---- stage 2: S <- gelu(S @ HW1[h]^T + Hb1[h])  (in place) ----
    const unsigned short* W2p = HW1b + (size_t)h * 65536;
    #pragma unroll
    for (int mt = 0; mt < 4; ++mt)
        #pragma unroll
        for (int nt = 0; nt < 4; ++nt) acc[mt][nt] = 0.f;
    {
        bf16x8 bn1[4], bn2[4];
        #pragma unroll
        for (int nt = 0; nt < 4; ++nt) {
            bn1[nt] = *(const bf16x8*)(W2p + (size_t)(w * 64 + nt * 16 + l15) * 256 + 0 * 32 + l4 * 8);
            bn2[nt] = *(const bf16x8*)(W2p + (size_t)(w * 64 + nt * 16 + l15) * 256 + 1 * 32 + l4 * 8);
        }
        for (int kc = 0; kc < 8; ++kc) {
            bf16x8 bcur[4];
            #pragma unroll
            for (int nt = 0; nt < 4; ++nt) { bcur[nt] = bn1[nt]; bn1[nt] = bn2[nt]; }
            if (kc < 6) {
                #pragma unroll
                for (int nt = 0; nt < 4; ++nt)
                    bn2[nt] = *(const bf16x8*)(W2p + (size_t)(w * 64 + nt * 16 + l15) * 256 + (kc + 2) * 32 + l4 * 8);
            }
            #pragma unroll
            for (int mt = 0; mt < 4; ++mt) {
                bf16x8 afr = *(const bf16x8*)&S[(mt * 16 + l15) * MPAD + kc * 32 + l4 * 8];
                #pragma unroll
                for (int nt = 0; nt < 4; ++nt)
                    acc[mt][nt] = __builtin_amdgcn_mfma_f32_16x16x32_bf16(afr, bcur[nt], acc[mt][nt], 0, 0, 0);
            }
        }
    }
    __syncthreads();
    #pragma unroll
    for (int nt = 0; nt < 4; ++nt) {
        int kk = w * 64 + nt * 16 + l15;
        float hb = Hb1[(size_t)h * 256 + kk];
        #pragma unroll
        for (int mt = 0; mt < 4; ++mt)
            #pragma unroll
            for (int r = 0; r < 4; ++r) {
                int c = mt * 16 + l4 * 4 + r;
                S[c * MPAD + kk] = f2bf(gelu_fast(acc[mt][nt][r] + hb));
            }
    }
    __syncthreads();

    // ---- stage 3: acc = S(=T) @ HW2[h]^T ----
    const unsigned short* W3p = HW2b + (size_t)h * 65536;
    #pragma unroll
    for (int mt = 0; mt < 4; ++mt)
        #pragma unroll
        for (int nt = 0; nt < 4; ++nt) acc[mt][nt] = 0.f;
    {
        bf16x8 bn1[4], bn2[4];
        #pragma unroll
        for (int nt = 0; nt < 4; ++nt) {
            bn1[nt] = *(const bf16x8*)(W3p + (size_t)(w * 64 + nt * 16 + l15) * 256 + 0 * 32 + l4 * 8);
            bn2[nt] = *(const bf16x8*)(W3p + (size_t)(w * 64 + nt * 16 + l15) * 256 + 1 * 32 + l4 * 8);
        }
        for (int kc = 0; kc < 8; ++kc) {
            bf16x8 bcur[4];
            #pragma unroll
            for (int nt = 0; nt < 4; ++nt) { bcur[nt] = bn1[nt]; bn1[nt] = bn2[nt]; }
            if (kc < 6) {
                #pragma unroll
                for (int nt = 0; nt < 4; ++nt)
                    bn2[nt] = *(const bf16x8*)(W3p + (size_t)(w * 64 + nt * 16 + l15) * 256 + (kc + 2) * 32 + l4 * 8);
            }
            #pragma unroll
            for (int mt = 0; mt < 4; ++mt) {
                bf16x8 afr = *(const bf16x8*)&S[(mt * 16 + l15) * MPAD + kc * 32 + l4 * 8];
                #pragma unroll
                for (int nt = 0; nt < 4; ++nt)
                    acc[mt][nt] = __builtin_amdgcn_mfma_f32_16x16x32_bf16(afr, bcur[nt], acc[mt][nt], 0, 0, 0);
            }
        }
    }
    __syncthreads();

    #pragma unroll
    for (int nt = 0; nt < 4; ++nt) {
        int p = w * 64 + nt * 16 + l15;
        float hb = Hb2[(size_t)h * 256 + p];
        #pragma unroll
        for (int mt = 0; mt < 4; ++mt) {
            int c0 = mt * 16 + l4 * 4;
            ushort4 uv;
            uv.x = f2bf(acc[mt][nt][0] + hb + bf2f(XT[(c0 + 0) * MPAD + p]));
            uv.y = f2bf(acc[mt][nt][1] + hb + bf2f(XT[(c0 + 1) * MPAD + p]));
            uv.z = f2bf(acc[mt][nt][2] + hb + bf2f(XT[(c0 + 2) * MPAD + p]));
            uv.w = f2bf(acc[mt][nt][3] + hb + bf2f(XT[(c0 + 3) * MPAD + p]));
            *(ushort4*)(ST + p * 68 + c0) = uv;
        }
    }
    __syncthreads();

    #pragma unroll
    for (int s = 0; s < 16; ++s) {
        int row = s * 16 + w * 4 + l4;
        ushort4 u = *(const ushort4*)(ST + row * 68 + l15 * 4);
        *(ushort4*)(Xb + ((size_t)(b * 256 + row)) * 512 + h * 64 + l15 * 4) = u;
    }
}

// ---------------------------------------------------------------------------
// GEMM v5 (m97 template, round-10/11 proven): 128x128 tile, BK=64,
// 256 threads / 4 waves, single 32KB buffer, ~3 blocks/CU.
// ---------------------------------------------------------------------------
DEV void stage_m97(const unsigned short* g, size_t gstride, int row0, int k0,
                   char* lbuf, int tid) {
    const int slot = tid & 7;
    const int r8 = (tid >> 3) & 7;
    const int wv = tid >> 6;
    const int swz = (slot ^ r8) * 16;
    #pragma unroll
    for (int i = 0; i < 4; ++i) {
        int chunk = i * 4 + wv;  // 0..15, wave-uniform
        int row = chunk * 8 + r8;
        const char* src = (const char*)(g + (size_t)(row0 + row) * gstride + k0) + swz;
        __builtin_amdgcn_global_load_lds((const glb_u32*)src,
                                         (lds_u32*)(lbuf + chunk * 1024), 16, 0, 0);
    }
}

DEV void gemm_loop97(const unsigned short* A, size_t sA,
                     const unsigned short* B, size_t sB,
                     int m0, int n0, int NT,
                     char* smem, int tid, f32x4 (&acc)[4][4]) {
    const int lane = tid & 63;
    const int w = tid >> 6;
    const int l15 = lane & 15, l4 = lane >> 4;
    const int wm = w >> 1, wn = w & 1;

    for (int t = 0; t < NT; ++t) {
        stage_m97(A, sA, m0, t * 64, smem, tid);
        stage_m97(B, sB, n0, t * 64, smem + 16384, tid);
        __syncthreads();
        #pragma unroll
        for (int kk = 0; kk < 2; ++kk) {
            bf16x8 af[4], bf[4];
            #pragma unroll
            for (int mf = 0; mf < 4; ++mf) {
                int row = wm * 64 + mf * 16 + l15;
                af[mf] = *(const bf16x8*)(smem + row * 128 + ((kk * 64 + l4 * 16) ^ ((row & 7) << 4)));
            }
            #pragma unroll
            for (int nf = 0; nf < 4; ++nf) {
                int row = wn * 64 + nf * 16 + l15;
                bf[nf] = *(const bf16x8*)(smem + 16384 + row * 128 + ((kk * 64 + l4 * 16) ^ ((row & 7) << 4)));
            }
            #pragma unroll
            for (int mf = 0; mf < 4; ++mf)
                #pragma unroll
                for (int nf = 0; nf < 4; ++nf)
                    acc[mf][nf] = __builtin_amdgcn_mfma_f32_16x16x32_bf16(
                        af[mf], bf[nf], acc[mf][nf], 0, 0, 0);
        }
        __syncthreads();
    }
}

// GEMM1: G = gelu(Xb @ FW1b^T + Fb1 + sc0*w512 + sc1*w513), LDS-bounce G store
__global__ __launch_bounds__(256, 3) void gemm1_kernel(
    const unsigned short* __restrict__ A,
    const unsigned short* __restrict__ B,
    const float* __restrict__ Fb1,
    const float* __restrict__ FW1,
    const float* __restrict__ scbuf,
    long pass_m0,
    unsigned short* __restrict__ G) {
    __shared__ __attribute__((aligned(16))) char smem[34816];

    const int nwg = gridDim.x;
    const int cpx = nwg >> 3;
    const int bid = (blockIdx.x & 7) * cpx + (blockIdx.x >> 3);
    const int m0 = (bid >> 4) * 128;
    const int n0 = (bid & 15) * 128;
    const int tid = threadIdx.x;
    const int lane = tid & 63;
    const int w = tid >> 6;
    const int l15 = lane & 15;
    const int l4 = lane >> 4;
    const int wm = w >> 1, wn = w & 1;

    f32x4 acc[4][4];
    #pragma unroll
    for (int mf = 0; mf < 4; ++mf)
        #pragma unroll
        for (int nf = 0; nf < 4; ++nf) acc[mf][nf] = 0.f;

    gemm_loop97(A, 512, B, 512, m0, n0, 8, smem, tid, acc);

    float fb[4], wa[4], wb[4];
    #pragma unroll
    for (int nf = 0; nf < 4; ++nf) {
        int n = n0 + wn * 64 + nf * 16 + l15;
        fb[nf] = Fb1[n];
        wa[nf] = FW1[(size_t)n * 514 + 512];
        wb[nf] = FW1[(size_t)n * 514 + 513];
    }
    f32x2 sc[4][4];
    #pragma unroll
    for (int mf = 0; mf < 4; ++mf)
        #pragma unroll
        for (int r = 0; r < 4; ++r) {
            long rowg = pass_m0 + m0 + wm * 64 + mf * 16 + l4 * 4 + r;
            sc[mf][r] = *(const f32x2*)(scbuf + rowg * 2);
        }
    unsigned short* LT = (unsigned short*)smem;  // [128][136]
    #pragma unroll
    for (int mf = 0; mf < 4; ++mf)
        #pragma unroll
        for (int nf = 0; nf < 4; ++nf)
            #pragma unroll
            for (int r = 0; r < 4; ++r) {
                float v = acc[mf][nf][r] + fb[nf] + sc[mf][r].x * wa[nf] + sc[mf][r].y * wb[nf];
                int rl = wm * 64 + mf * 16 + l4 * 4 + r;
                LT[rl * 136 + wn * 64 + nf * 16 + l15] = f2bf(gelu_fast(v));
            }
    __syncthreads();
    {
        const int lane16 = tid & 15, rowq = tid >> 4;
        #pragma unroll
        for (int s = 0; s < 8; ++s) {
            int row = s * 16 + rowq;
            uint4 d = *(const uint4*)((const char*)smem + row * 272 + lane16 * 16);
            *(uint4*)(G + ((size_t)(m0 + row)) * 2048 + n0 + lane16 * 8) = d;
        }
    }
}

// GEMM2: io[., 0..511] = G @ FW2b^T + Fb2 + bf2f(Xb)   (residual from Xb)
__global__ __launch_bounds__(256, 3) void gemm2_kernel(
    const unsigned short* __restrict__ A,
    const unsigned short* __restrict__ B,
    const float* __restrict__ Fb2,
    const unsigned short* __restrict__ Xb,
    long pass_m0,
    float* __restrict__ io) {
    __shared__ __attribute__((aligned(16))) char smem[32768];

    const int nwg = gridDim.x;
    const int cpx = nwg >> 3;
    const int bid = (blockIdx.x & 7) * cpx + (blockIdx.x >> 3);
    const int m0 = (bid >> 2) * 128;
    const int n0 = (bid & 3) * 128;
    const int tid = threadIdx.x;
    const int lane = tid & 63;
    const int w = tid >> 6;
    const int l15 = lane & 15;
    const int l4 = lane >> 4;
    const int wm = w >> 1, wn = w & 1;

    f32x4 acc[4][4];
    #pragma unroll
    for (int mf = 0; mf < 4; ++mf)
        #pragma unroll
        for (int nf = 0; nf < 4; ++nf) acc[mf][nf] = 0.f;

    gemm_loop97(A, 2048, B, 2048, m0, n0, 32, smem, tid, acc);

    #pragma unroll
    for (int nf = 0; nf < 4; ++nf) {
        int n = n0 + wn * 64 + nf * 16 + l15;
        float fbv = Fb2[n];
        #pragma unroll
        for (int mf = 0; mf < 4; ++mf)
            #pragma unroll
            for (int r = 0; r < 4; ++r) {
                long rowg = pass_m0 + m0 + wm * 64 + mf * 16 + l4 * 4 + r;
                float resv = bf2f(Xb[(size_t)rowg * 512 + n]);
                io[rowg * 514 + n] = acc[mf][nf][r] + fbv + resv;
            }
    }
}

// ---------------------------------------------------------------------------
extern "C" void kernel_launch(void* const* d_in, const int* in_sizes, int n_in,
                              void* d_out, int out_size, void* d_ws, size_t ws_size,
                              hipStream_t stream) {
    const float* x = (const float*)d_in[0];
    const float* Ws = (const float*)d_in[1];
    const float* bs = (const float*)d_in[2];
    const float* LW1 = (const float*)d_in[3];
    const float* Lb1 = (const float*)d_in[4];
    const float* LW2 = (const float*)d_in[5];
    const float* Lb2 = (const float*)d_in[6];
    const float* HW1 = (const float*)d_in[7];
    const float* Hb1 = (const float*)d_in[8];
    const float* HW2 = (const float*)d_in[9];
    const float* Hb2 = (const float*)d_in[10];
    const float* FW1 = (const float*)d_in[11];
    const float* Fb1 = (const float*)d_in[12];
    const float* FW2 = (const float*)d_in[13];
    const float* Fb2 = (const float*)d_in[14];
    float* out = (float*)d_out;

    char* ws = (char*)d_ws;
    unsigned short* Wsb = (unsigned short*)(ws);                 // 131072 B
    unsigned short* HW1b = (unsigned short*)(ws + 131072);       // 1048576 B
    unsigned short* HW2b = (unsigned short*)(ws + 1179648);      // 1048576 B
    unsigned short* FW1b = (unsigned short*)(ws + 2228224);      // 2097152 B
    unsigned short* FW2b = (unsigned short*)(ws + 4325376);      // 2097152 B
    float* gb = (float*)(ws + 6422528);                          // 524288 B
    float* scbuf = (float*)(ws + 6946816);                       // 524288 B
    unsigned short* Xb = (unsigned short*)(ws + 7471104);        // 67108864 B
    unsigned short* Gbuf = (unsigned short*)(ws + 7471104 + 67108864);

    const size_t fixed = 7471104 + 67108864;
    int npass = 32;
    for (int np = 2; np <= 32; np *= 2) {
        if (fixed + (size_t)268435456 / np <= ws_size) { npass = np; break; }
    }
    const long Mtot = 65536;
    const long Mp = Mtot / npass;

    cast_bf16_kernel<<<256, 256, 0, stream>>>(Ws, Wsb, 65536);
    cast_bf16_kernel<<<2048, 256, 0, stream>>>(HW1, HW1b, 524288);
    cast_bf16_kernel<<<2048, 256, 0, stream>>>(HW2, HW2b, 524288);
    cast_bf16_kernel<<<4096, 256, 0, stream>>>(FW2, FW2b, 1048576);
    cast_fw1_kernel<<<4096, 256, 0, stream>>>(FW1, FW1b);
    gb_kernel<<<32, 256, 0, stream>>>(x, LW1, Lb1, LW2, Lb2, gb);
    sc_copy_kernel<<<256, 256, 0, stream>>>(x, out, scbuf);

    mixer_kernel<<<2048, 256, 0, stream>>>(x, bs, Hb1, Hb2, Wsb, HW1b, HW2b, gb, Xb);

    for (int p = 0; p < npass; ++p) {
        long m0 = (long)p * Mp;
        gemm1_kernel<<<(int)(Mp / 128) * 16, 256, 0, stream>>>(
            Xb + m0 * 512, FW1b, Fb1, FW1, scbuf, m0, Gbuf);
        gemm2_kernel<<<(int)(Mp / 128) * 4, 256, 0, stream>>>(
            Gbuf, FW2b, Fb2, Xb, m0, out);
    }
}

// Round 16
// 587.490 us; speedup vs baseline: 1.0858x; 1.0176x over previous
//
#include <hip/hip_runtime.h>
#include <math.h>

typedef __attribute__((ext_vector_type(8))) __bf16 bf16x8;
typedef __attribute__((ext_vector_type(4))) float f32x4;
typedef __attribute__((ext_vector_type(2))) float f32x2;

#define DEV __device__ __forceinline__

typedef __attribute__((address_space(3))) unsigned int lds_u32;
typedef __attribute__((address_space(1))) unsigned int glb_u32;

DEV unsigned short f2bf(float f) {
    unsigned int u = __builtin_bit_cast(unsigned int, f);
    u += 0x7FFFu + ((u >> 16) & 1u);
    return (unsigned short)(u >> 16);
}
DEV float bf2f(unsigned short u) {
    unsigned int v = (unsigned int)u << 16;
    return __builtin_bit_cast(float, v);
}
DEV unsigned int pack2(float a, float b) {
    return (unsigned int)f2bf(a) | ((unsigned int)f2bf(b) << 16);
}
DEV float gelu_exact(float v) {
    return 0.5f * v * (1.0f + erff(v * 0.70710678118654752f));
}
// tanh-form gelu via sigmoid: x * sigmoid(1.595769x + 0.0713548x^3); |err| <= 3e-3
DEV float gelu_fast(float x) {
    float z = 1.5957691216f * x + 0.0713548163f * x * x * x;
    float e = __expf(-z);
    return x * __builtin_amdgcn_rcpf(1.0f + e);
}

// ---------------------------------------------------------------------------
// small prep kernels
// ---------------------------------------------------------------------------
__global__ void cast_bf16_kernel(const float* __restrict__ src,
                                 unsigned short* __restrict__ dst, int n) {
    int i = blockIdx.x * 256 + threadIdx.x;
    if (i < n) dst[i] = f2bf(src[i]);
}

__global__ void cast_fw1_kernel(const float* __restrict__ src,
                                unsigned short* __restrict__ dst) {
    int i = blockIdx.x * 256 + threadIdx.x;
    if (i < 2048 * 512) {
        int row = i >> 9, k = i & 511;
        dst[i] = f2bf(src[row * 514 + k]);
    }
}

__global__ void gb_kernel(const float* __restrict__ x,
                          const float* __restrict__ LW1, const float* __restrict__ Lb1,
                          const float* __restrict__ LW2, const float* __restrict__ Lb2,
                          float* __restrict__ gb) {
    __shared__ float t[8][512];
    const int b0 = blockIdx.x * 8, tid = threadIdx.x;
    for (int idx = tid; idx < 8 * 512; idx += 256) {
        int bb = idx >> 9, j = idx & 511;
        float s0 = x[((size_t)(b0 + bb) * 256 + 128) * 514 + 512];
        float s1 = x[((size_t)(b0 + bb) * 256 + 128) * 514 + 513];
        t[bb][j] = gelu_exact(LW1[j * 2] * s0 + LW1[j * 2 + 1] * s1 + Lb1[j]);
    }
    __syncthreads();
    const int i = tid;
    float a0[8], a1[8];
    float l0 = Lb2[i], l1 = Lb2[i + 256];
    #pragma unroll
    for (int bb = 0; bb < 8; ++bb) { a0[bb] = l0; a1[bb] = l1; }
    for (int j = 0; j < 512; ++j) {
        float w0 = LW2[(size_t)i * 512 + j];
        float w1 = LW2[(size_t)(i + 256) * 512 + j];
        #pragma unroll
        for (int bb = 0; bb < 8; ++bb) {
            a0[bb] += w0 * t[bb][j];
            a1[bb] += w1 * t[bb][j];
        }
    }
    #pragma unroll
    for (int bb = 0; bb < 8; ++bb) {
        gb[(size_t)(b0 + bb) * 512 + i] = a0[bb];
        gb[(size_t)(b0 + bb) * 512 + i + 256] = a1[bb];
    }
}

__global__ void sc_copy_kernel(const float* __restrict__ x, float* __restrict__ out,
                               float* __restrict__ scbuf) {
    size_t idx = (size_t)blockIdx.x * 256 + threadIdx.x;
    size_t off = idx * 514 + 512;
    f32x2 v = *(const f32x2*)(x + off);
    *(f32x2*)(out + off) = v;
    *(f32x2*)(scbuf + idx * 2) = v;
}

// ---------------------------------------------------------------------------
// mixer v8 (round-11 proven): two-phase x staging, 2-deep B prefetch.
// ---------------------------------------------------------------------------
#define MPAD 264

__global__ __launch_bounds__(256, 2) void mixer_kernel(
    const float* __restrict__ x, const float* __restrict__ bs,
    const float* __restrict__ Hb1, const float* __restrict__ Hb2,
    const unsigned short* __restrict__ Wsb,
    const unsigned short* __restrict__ HW1b,
    const unsigned short* __restrict__ HW2b,
    const float* __restrict__ gb,
    unsigned short* __restrict__ Xb) {
    __shared__ __attribute__((aligned(16))) char smem[33792 + 34816];
    unsigned short* XT = (unsigned short*)smem;
    unsigned short* S = (unsigned short*)(smem + 33792);
    unsigned short* ST = S;

    const int bid = blockIdx.x;
    const int b = bid >> 3;
    const int h = bid & 7;
    const int tid = threadIdx.x;
    const int lane = tid & 63;
    const int w = tid >> 6;
    const int l15 = lane & 15;
    const int l4 = lane >> 4;

    {
        const int c = lane;
        const float* xp = x + ((size_t)b * 256) * 514 + (size_t)h * 64 + c;
        float v[64];
        #pragma unroll
        for (int p = 0; p < 64; ++p)
            v[p] = xp[(size_t)(w * 64 + p) * 514];
        #pragma unroll
        for (int g = 0; g < 8; ++g) {
            uint4 pk;
            pk.x = pack2(v[g * 8 + 0], v[g * 8 + 1]);
            pk.y = pack2(v[g * 8 + 2], v[g * 8 + 3]);
            pk.z = pack2(v[g * 8 + 4], v[g * 8 + 5]);
            pk.w = pack2(v[g * 8 + 6], v[g * 8 + 7]);
            *(uint4*)&XT[c * MPAD + w * 64 + g * 8] = pk;
        }
    }
    __syncthreads();

    f32x4 acc[4][4];

    #pragma unroll
    for (int mt = 0; mt < 4; ++mt)
        #pragma unroll
        for (int nt = 0; nt < 4; ++nt) acc[mt][nt] = 0.f;
    {
        const unsigned short* Wp = Wsb;
        bf16x8 bn1[4], bn2[4];
        #pragma unroll
        for (int nt = 0; nt < 4; ++nt) {
            bn1[nt] = *(const bf16x8*)(Wp + (size_t)(w * 64 + nt * 16 + l15) * 256 + 0 * 32 + l4 * 8);
            bn2[nt] = *(const bf16x8*)(Wp + (size_t)(w * 64 + nt * 16 + l15) * 256 + 1 * 32 + l4 * 8);
        }
        for (int kc = 0; kc < 8; ++kc) {
            bf16x8 bcur[4];
            #pragma unroll
            for (int nt = 0; nt < 4; ++nt) { bcur[nt] = bn1[nt]; bn1[nt] = bn2[nt]; }
            if (kc < 6) {
                #pragma unroll
                for (int nt = 0; nt < 4; ++nt)
                    bn2[nt] = *(const bf16x8*)(Wp + (size_t)(w * 64 + nt * 16 + l15) * 256 + (kc + 2) * 32 + l4 * 8);
            }
            #pragma unroll
            for (int mt = 0; mt < 4; ++mt) {
                bf16x8 afr = *(const bf16x8*)&XT[(mt * 16 + l15) * MPAD + kc * 32 + l4 * 8];
                #pragma unroll
                for (int nt = 0; nt < 4; ++nt)
                    acc[mt][nt] = __builtin_amdgcn_mfma_f32_16x16x32_bf16(afr, bcur[nt], acc[mt][nt], 0, 0, 0);
            }
        }
    }
    #pragma unroll
    for (int nt = 0; nt < 4; ++nt) {
        int o = w * 64 + nt * 16 + l15;
        float bsv = bs[o];
        float g = gb[(size_t)b * 512 + o];
        float be = gb[(size_t)b * 512 + 256 + o];
        #pragma unroll
        for (int mt = 0; mt < 4; ++mt)
            #pragma unroll
            for (int r = 0; r < 4; ++r) {
                int c = mt * 16 + l4 * 4 + r;
                S[c * MPAD + o] = f2bf((acc[mt][nt][r] + bsv) * g + be);
            }
    }
    __syncthreads();

    const unsigned short* W2p = HW1b + (size_t)h * 65536;
    #pragma unroll
    for (int mt = 0; mt < 4; ++mt)
        #pragma unroll
        for (int nt = 0; nt < 4; ++nt) acc[mt][nt] = 0.f;
    {
        bf16x8 bn1[4], bn2[4];
        #pragma unroll
        for (int nt = 0; nt < 4; ++nt) {
            bn1[nt] = *(const bf16x8*)(W2p + (size_t)(w * 64 + nt * 16 + l15) * 256 + 0 * 32 + l4 * 8);
            bn2[nt] = *(const bf16x8*)(W2p + (size_t)(w * 64 + nt * 16 + l15) * 256 + 1 * 32 + l4 * 8);
        }
        for (int kc = 0; kc < 8; ++kc) {
            bf16x8 bcur[4];
            #pragma unroll
            for (int nt = 0; nt < 4; ++nt) { bcur[nt] = bn1[nt]; bn1[nt] = bn2[nt]; }
            if (kc < 6) {
                #pragma unroll
                for (int nt = 0; nt < 4; ++nt)
                    bn2[nt] = *(const bf16x8*)(W2p + (size_t)(w * 64 + nt * 16 + l15) * 256 + (kc + 2) * 32 + l4 * 8);
            }
            #pragma unroll
            for (int mt = 0; mt < 4; ++mt) {
                bf16x8 afr = *(const bf16x8*)&S[(mt * 16 + l15) * MPAD + kc * 32 + l4 * 8];
                #pragma unroll
                for (int nt = 0; nt < 4; ++nt)
                    acc[mt][nt] = __builtin_amdgcn_mfma_f32_16x16x32_bf16(afr, bcur[nt], acc[mt][nt], 0, 0, 0);
            }
        }
    }
    __syncthreads();
    #pragma unroll
    for (int nt = 0; nt < 4; ++nt) {
        int kk = w * 64 + nt * 16 + l15;
        float hb = Hb1[(size_t)h * 256 + kk];
        #pragma unroll
        for (int mt = 0; mt < 4; ++mt)
            #pragma unroll
            for (int r = 0; r < 4; ++r) {
                int c = mt * 16 + l4 * 4 + r;
                S[c * MPAD + kk] = f2bf(gelu_fast(acc[mt][nt][r] + hb));
            }
    }
    __syncthreads();

    const unsigned short* W3p = HW2b + (size_t)h * 65536;
    #pragma unroll
    for (int mt = 0; mt < 4; ++mt)
        #pragma unroll
        for (int nt = 0; nt < 4; ++nt) acc[mt][nt] = 0.f;
    {
        bf16x8 bn1[4], bn2[4];
        #pragma unroll
        for (int nt = 0; nt < 4; ++nt) {
            bn1[nt] = *(const bf16x8*)(W3p + (size_t)(w * 64 + nt * 16 + l15) * 256 + 0 * 32 + l4 * 8);
            bn2[nt] = *(const bf16x8*)(W3p + (size_t)(w * 64 + nt * 16 + l15) * 256 + 1 * 32 + l4 * 8);
        }
        for (int kc = 0; kc < 8; ++kc) {
            bf16x8 bcur[4];
            #pragma unroll
            for (int nt = 0; nt < 4; ++nt) { bcur[nt] = bn1[nt]; bn1[nt] = bn2[nt]; }
            if (kc < 6) {
                #pragma unroll
                for (int nt = 0; nt < 4; ++nt)
                    bn2[nt] = *(const bf16x8*)(W3p + (size_t)(w * 64 + nt * 16 + l15) * 256 + (kc + 2) * 32 + l4 * 8);
            }
            #pragma unroll
            for (int mt = 0; mt < 4; ++mt) {
                bf16x8 afr = *(const bf16x8*)&S[(mt * 16 + l15) * MPAD + kc * 32 + l4 * 8];
                #pragma unroll
                for (int nt = 0; nt < 4; ++nt)
                    acc[mt][nt] = __builtin_amdgcn_mfma_f32_16x16x32_bf16(afr, bcur[nt], acc[mt][nt], 0, 0, 0);
            }
        }
    }
    __syncthreads();

    #pragma unroll
    for (int nt = 0; nt < 4; ++nt) {
        int p = w * 64 + nt * 16 + l15;
        float hb = Hb2[(size_t)h * 256 + p];
        #pragma unroll
        for (int mt = 0; mt < 4; ++mt) {
            int c0 = mt * 16 + l4 * 4;
            ushort4 uv;
            uv.x = f2bf(acc[mt][nt][0] + hb + bf2f(XT[(c0 + 0) * MPAD + p]));
            uv.y = f2bf(acc[mt][nt][1] + hb + bf2f(XT[(c0 + 1) * MPAD + p]));
            uv.z = f2bf(acc[mt][nt][2] + hb + bf2f(XT[(c0 + 2) * MPAD + p]));
            uv.w = f2bf(acc[mt][nt][3] + hb + bf2f(XT[(c0 + 3) * MPAD + p]));
            *(ushort4*)(ST + p * 68 + c0) = uv;
        }
    }
    __syncthreads();

    #pragma unroll
    for (int s = 0; s < 16; ++s) {
        int row = s * 16 + w * 4 + l4;
        ushort4 u = *(const ushort4*)(ST + row * 68 + l15 * 4);
        *(ushort4*)(Xb + ((size_t)(b * 256 + row)) * 512 + h * 64 + l15 * 4) = u;
    }
}

// ---------------------------------------------------------------------------
// GEMM v5 (m97 template, round-10/11 proven): 128x128 tile, BK=64,
// 256 threads / 4 waves, single 32KB buffer, ~3 blocks/CU.
// ---------------------------------------------------------------------------
DEV void stage_m97(const unsigned short* g, size_t gstride, int row0, int k0,
                   char* lbuf, int tid) {
    const int slot = tid & 7;
    const int r8 = (tid >> 3) & 7;
    const int wv = tid >> 6;
    const int swz = (slot ^ r8) * 16;
    #pragma unroll
    for (int i = 0; i < 4; ++i) {
        int chunk = i * 4 + wv;  // 0..15, wave-uniform
        int row = chunk * 8 + r8;
        const char* src = (const char*)(g + (size_t)(row0 + row) * gstride + k0) + swz;
        __builtin_amdgcn_global_load_lds((const glb_u32*)src,
                                         (lds_u32*)(lbuf + chunk * 1024), 16, 0, 0);
    }
}

DEV void gemm_loop97(const unsigned short* A, size_t sA,
                     const unsigned short* B, size_t sB,
                     int m0, int n0, int NT,
                     char* smem, int tid, f32x4 (&acc)[4][4]) {
    const int lane = tid & 63;
    const int w = tid >> 6;
    const int l15 = lane & 15, l4 = lane >> 4;
    const int wm = w >> 1, wn = w & 1;

    for (int t = 0; t < NT; ++t) {
        stage_m97(A, sA, m0, t * 64, smem, tid);
        stage_m97(B, sB, n0, t * 64, smem + 16384, tid);
        __syncthreads();
        #pragma unroll
        for (int kk = 0; kk < 2; ++kk) {
            bf16x8 af[4], bf[4];
            #pragma unroll
            for (int mf = 0; mf < 4; ++mf) {
                int row = wm * 64 + mf * 16 + l15;
                af[mf] = *(const bf16x8*)(smem + row * 128 + ((kk * 64 + l4 * 16) ^ ((row & 7) << 4)));
            }
            #pragma unroll
            for (int nf = 0; nf < 4; ++nf) {
                int row = wn * 64 + nf * 16 + l15;
                bf[nf] = *(const bf16x8*)(smem + 16384 + row * 128 + ((kk * 64 + l4 * 16) ^ ((row & 7) << 4)));
            }
            #pragma unroll
            for (int mf = 0; mf < 4; ++mf)
                #pragma unroll
                for (int nf = 0; nf < 4; ++nf)
                    acc[mf][nf] = __builtin_amdgcn_mfma_f32_16x16x32_bf16(
                        af[mf], bf[nf], acc[mf][nf], 0, 0, 0);
        }
        __syncthreads();
    }
}

// GEMM1: G = gelu(Xb @ FW1b^T + Fb1 + sc0*w512 + sc1*w513), LDS-bounce G store
__global__ __launch_bounds__(256, 3) void gemm1_kernel(
    const unsigned short* __restrict__ A,
    const unsigned short* __restrict__ B,
    const float* __restrict__ Fb1,
    const float* __restrict__ FW1,
    const float* __restrict__ scbuf,
    long pass_m0,
    unsigned short* __restrict__ G) {
    __shared__ __attribute__((aligned(16))) char smem[34816];

    const int nwg = gridDim.x;
    const int cpx = nwg >> 3;
    const int bid = (blockIdx.x & 7) * cpx + (blockIdx.x >> 3);
    const int m0 = (bid >> 4) * 128;
    const int n0 = (bid & 15) * 128;
    const int tid = threadIdx.x;
    const int lane = tid & 63;
    const int w = tid >> 6;
    const int l15 = lane & 15;
    const int l4 = lane >> 4;
    const int wm = w >> 1, wn = w & 1;

    f32x4 acc[4][4];
    #pragma unroll
    for (int mf = 0; mf < 4; ++mf)
        #pragma unroll
        for (int nf = 0; nf < 4; ++nf) acc[mf][nf] = 0.f;

    gemm_loop97(A, 512, B, 512, m0, n0, 8, smem, tid, acc);

    float fb[4], wa[4], wb[4];
    #pragma unroll
    for (int nf = 0; nf < 4; ++nf) {
        int n = n0 + wn * 64 + nf * 16 + l15;
        fb[nf] = Fb1[n];
        wa[nf] = FW1[(size_t)n * 514 + 512];
        wb[nf] = FW1[(size_t)n * 514 + 513];
    }
    f32x2 sc[4][4];
    #pragma unroll
    for (int mf = 0; mf < 4; ++mf)
        #pragma unroll
        for (int r = 0; r < 4; ++r) {
            long rowg = pass_m0 + m0 + wm * 64 + mf * 16 + l4 * 4 + r;
            sc[mf][r] = *(const f32x2*)(scbuf + rowg * 2);
        }
    unsigned short* LT = (unsigned short*)smem;  // [128][136]
    #pragma unroll
    for (int mf = 0; mf < 4; ++mf)
        #pragma unroll
        for (int nf = 0; nf < 4; ++nf)
            #pragma unroll
            for (int r = 0; r < 4; ++r) {
                float v = acc[mf][nf][r] + fb[nf] + sc[mf][r].x * wa[nf] + sc[mf][r].y * wb[nf];
                int rl = wm * 64 + mf * 16 + l4 * 4 + r;
                LT[rl * 136 + wn * 64 + nf * 16 + l15] = f2bf(gelu_fast(v));
            }
    __syncthreads();
    {
        const int lane16 = tid & 15, rowq = tid >> 4;
        #pragma unroll
        for (int s = 0; s < 8; ++s) {
            int row = s * 16 + rowq;
            uint4 d = *(const uint4*)((const char*)smem + row * 272 + lane16 * 16);
            *(uint4*)(G + ((size_t)(m0 + row)) * 2048 + n0 + lane16 * 8) = d;
        }
    }
}

// GEMM2: io[., 0..511] = G @ FW2b^T + Fb2 + bf2f(Xb)
// v2 epilogue: LDS bounce (4 chunks of 32 rows), coalesced Xb reads (uint4)
// and io writes (f32x2 bursts, 512B/row across 8 threads).
__global__ __launch_bounds__(256, 3) void gemm2_kernel(
    const unsigned short* __restrict__ A,
    const unsigned short* __restrict__ B,
    const float* __restrict__ Fb2,
    const unsigned short* __restrict__ Xb,
    long pass_m0,
    float* __restrict__ io) {
    __shared__ __attribute__((aligned(16))) char smem[32768];

    const int nwg = gridDim.x;
    const int cpx = nwg >> 3;
    const int bid = (blockIdx.x & 7) * cpx + (blockIdx.x >> 3);
    const int m0 = (bid >> 2) * 128;
    const int n0 = (bid & 3) * 128;
    const int tid = threadIdx.x;
    const int lane = tid & 63;
    const int w = tid >> 6;
    const int l15 = lane & 15;
    const int l4 = lane >> 4;
    const int wm = w >> 1, wn = w & 1;

    f32x4 acc[4][4];
    #pragma unroll
    for (int mf = 0; mf < 4; ++mf)
        #pragma unroll
        for (int nf = 0; nf < 4; ++nf) acc[mf][nf] = 0.f;

    gemm_loop97(A, 2048, B, 2048, m0, n0, 32, smem, tid, acc);

    float fb[4];
    #pragma unroll
    for (int nf = 0; nf < 4; ++nf)
        fb[nf] = Fb2[n0 + wn * 64 + nf * 16 + l15];

    float* LT = (float*)smem;  // [32][130] per chunk
    #pragma unroll
    for (int ck = 0; ck < 4; ++ck) {
        // waves with wm == ck>>1 own these 32 rows; mf pair = (ck&1)*2, +1
        if (wm == (ck >> 1)) {
            #pragma unroll
            for (int mi = 0; mi < 2; ++mi) {
                int mf = (ck & 1) * 2 + mi;
                #pragma unroll
                for (int nf = 0; nf < 4; ++nf)
                    #pragma unroll
                    for (int r = 0; r < 4; ++r) {
                        int rloc = mf * 16 + l4 * 4 + r - (ck & 1) * 32;  // 0..31
                        LT[rloc * 130 + wn * 64 + nf * 16 + l15] = acc[mf][nf][r] + fb[nf];
                    }
            }
        }
        __syncthreads();
        {
            const int row = tid >> 3;   // 0..31
            const int seg = tid & 7;    // 16 cols each
            long grow = pass_m0 + m0 + ck * 32 + row;
            const float* lt = &LT[row * 130 + seg * 16];
            // residual: 16 bf16 = 32B, 16B-aligned (n0%128==0, seg*32B)
            uint4 xr0 = *(const uint4*)(Xb + (size_t)grow * 512 + n0 + seg * 16);
            uint4 xr1 = *(const uint4*)(Xb + (size_t)grow * 512 + n0 + seg * 16 + 8);
            float* op = io + (size_t)grow * 514 + n0 + seg * 16;
            const unsigned short* xp0 = (const unsigned short*)&xr0;
            const unsigned short* xp1 = (const unsigned short*)&xr1;
            #pragma unroll
            for (int j = 0; j < 4; ++j) {
                f32x2 v;
                v.x = lt[j * 2 + 0] + bf2f(xp0[j * 2 + 0]);
                v.y = lt[j * 2 + 1] + bf2f(xp0[j * 2 + 1]);
                *(f32x2*)(op + j * 2) = v;
            }
            #pragma unroll
            for (int j = 0; j < 4; ++j) {
                f32x2 v;
                v.x = lt[8 + j * 2 + 0] + bf2f(xp1[j * 2 + 0]);
                v.y = lt[8 + j * 2 + 1] + bf2f(xp1[j * 2 + 1]);
                *(f32x2*)(op + 8 + j * 2) = v;
            }
        }
        __syncthreads();
    }
}

// ---------------------------------------------------------------------------
extern "C" void kernel_launch(void* const* d_in, const int* in_sizes, int n_in,
                              void* d_out, int out_size, void* d_ws, size_t ws_size,
                              hipStream_t stream) {
    const float* x = (const float*)d_in[0];
    const float* Ws = (const float*)d_in[1];
    const float* bs = (const float*)d_in[2];
    const float* LW1 = (const float*)d_in[3];
    const float* Lb1 = (const float*)d_in[4];
    const float* LW2 = (const float*)d_in[5];
    const float* Lb2 = (const float*)d_in[6];
    const float* HW1 = (const float*)d_in[7];
    const float* Hb1 = (const float*)d_in[8];
    const float* HW2 = (const float*)d_in[9];
    const float* Hb2 = (const float*)d_in[10];
    const float* FW1 = (const float*)d_in[11];
    const float* Fb1 = (const float*)d_in[12];
    const float* FW2 = (const float*)d_in[13];
    const float* Fb2 = (const float*)d_in[14];
    float* out = (float*)d_out;

    char* ws = (char*)d_ws;
    unsigned short* Wsb = (unsigned short*)(ws);                 // 131072 B
    unsigned short* HW1b = (unsigned short*)(ws + 131072);       // 1048576 B
    unsigned short* HW2b = (unsigned short*)(ws + 1179648);      // 1048576 B
    unsigned short* FW1b = (unsigned short*)(ws + 2228224);      // 2097152 B
    unsigned short* FW2b = (unsigned short*)(ws + 4325376);      // 2097152 B
    float* gb = (float*)(ws + 6422528);                          // 524288 B
    float* scbuf = (float*)(ws + 6946816);                       // 524288 B
    unsigned short* Xb = (unsigned short*)(ws + 7471104);        // 67108864 B
    unsigned short* Gbuf = (unsigned short*)(ws + 7471104 + 67108864);

    const size_t fixed = 7471104 + 67108864;
    int npass = 32;
    for (int np = 2; np <= 32; np *= 2) {
        if (fixed + (size_t)268435456 / np <= ws_size) { npass = np; break; }
    }
    const long Mtot = 65536;
    const long Mp = Mtot / npass;

    cast_bf16_kernel<<<256, 256, 0, stream>>>(Ws, Wsb, 65536);
    cast_bf16_kernel<<<2048, 256, 0, stream>>>(HW1, HW1b, 524288);
    cast_bf16_kernel<<<2048, 256, 0, stream>>>(HW2, HW2b, 524288);
    cast_bf16_kernel<<<4096, 256, 0, stream>>>(FW2, FW2b, 1048576);
    cast_fw1_kernel<<<4096, 256, 0, stream>>>(FW1, FW1b);
    gb_kernel<<<32, 256, 0, stream>>>(x, LW1, Lb1, LW2, Lb2, gb);
    sc_copy_kernel<<<256, 256, 0, stream>>>(x, out, scbuf);

    mixer_kernel<<<2048, 256, 0, stream>>>(x, bs, Hb1, Hb2, Wsb, HW1b, HW2b, gb, Xb);

    for (int p = 0; p < npass; ++p) {
        long m0 = (long)p * Mp;
        gemm1_kernel<<<(int)(Mp / 128) * 16, 256, 0, stream>>>(
            Xb + m0 * 512, FW1b, Fb1, FW1, scbuf, m0, Gbuf);
        gemm2_kernel<<<(int)(Mp / 128) * 4, 256, 0, stream>>>(
            Gbuf, FW2b, Fb2, Xb, m0, out);
    }
}